// Round 15
// baseline (435.367 us; speedup 1.0000x reference)
//
#include <hip/hip_runtime.h>
#include <hip/hip_bf16.h>

// Problem constants
#define BB 32
#define QQ 300
#define DD 256
#define HH 8
#define DHH 32
#define LL 4
#define PP 4
#define SS 8500

typedef __attribute__((ext_vector_type(8))) short bf16x8;
typedef __attribute__((ext_vector_type(4))) float f32x4;

__device__ inline unsigned short f2bf(float f) {
  unsigned int u = __builtin_bit_cast(unsigned int, f);
  unsigned int r = (u + 0x7FFFu + ((u >> 16) & 1u)) >> 16;
  return (unsigned short)r;
}

// ---------------------------------------------------------------------------
// Convert W_val (256x256 f32, [k][n]) -> bf16 [n][k] with T2 XOR swizzle
// ---------------------------------------------------------------------------
__global__ __launch_bounds__(256) void wcvt_kernel(const float* __restrict__ W,
                                                   unsigned short* __restrict__ wbfS) {
  int t = blockIdx.x * 256 + threadIdx.x;   // 0..65535
  int k = t >> 8, n = t & 255;              // coalesced read of W[k][*]
  wbfS[n * 256 + (k ^ ((n & 7) << 3))] = f2bf(W[(size_t)k * 256 + n]);
}

// ---------------------------------------------------------------------------
// Value GEMM (unchanged — 4 blocks/CU, ~4.9 TB/s effective):
// C[M x 256] = bf16(A[M x 256] f32) @ bf16(W) + bias.
// ---------------------------------------------------------------------------
__global__ __launch_bounds__(256, 4) void gemm_val_mfma(
    const float* __restrict__ A, const unsigned short* __restrict__ WbfS,
    const float* __restrict__ bias, __hip_bfloat16* __restrict__ C) {
  __shared__ __align__(16) unsigned short Alds[64 * 64];  // 8 KB, swizzled
  __shared__ __align__(16) unsigned short Blds[256 * 64]; // 32 KB, swizzled

  const int t = threadIdx.x;
  const int lane = t & 63;
  const int w = t >> 6;
  const int lm = lane & 15, lg = lane >> 4;
  const int row0 = blockIdx.x * 64;

  f32x4 acc[16];
#pragma unroll
  for (int nf = 0; nf < 16; ++nf) acc[nf] = {0.f, 0.f, 0.f, 0.f};

  for (int k0 = 0; k0 < 256; k0 += 64) {
#pragma unroll
    for (int i = 0; i < 8; ++i) {
      const unsigned short* gp = WbfS +
          (size_t)(w * 64 + i * 8 + (lane >> 3)) * 256 + k0 + (lane & 7) * 8;
      unsigned char* lp = reinterpret_cast<unsigned char*>(Blds) + (w * 8 + i) * 1024;
      __builtin_amdgcn_global_load_lds(
          (const __attribute__((address_space(1))) void*)gp,
          (__attribute__((address_space(3))) void*)lp, 16, 0, 0);
    }
#pragma unroll
    for (int i = 0; i < 4; ++i) {
      int u = i * 256 + t;
      int r = u >> 4, c4 = (u & 15) * 4;
      float4 v = *reinterpret_cast<const float4*>(A + (size_t)(row0 + r) * 256 + k0 + c4);
      ushort4 h;
      h.x = f2bf(v.x); h.y = f2bf(v.y); h.z = f2bf(v.z); h.w = f2bf(v.w);
      *reinterpret_cast<ushort4*>(&Alds[r * 64 + (c4 ^ ((r & 7) << 3))]) = h;
    }
    __syncthreads();

#pragma unroll
    for (int ks = 0; ks < 2; ++ks) {
      const int kk = (ks * 32 + lg * 8) ^ ((lm & 7) << 3);
      const bf16x8 af = *reinterpret_cast<const bf16x8*>(&Alds[(w * 16 + lm) * 64 + kk]);
#pragma unroll
      for (int nf = 0; nf < 16; ++nf) {
        const bf16x8 bfr = *reinterpret_cast<const bf16x8*>(&Blds[(nf * 16 + lm) * 64 + kk]);
        acc[nf] = __builtin_amdgcn_mfma_f32_16x16x32_bf16(af, bfr, acc[nf], 0, 0, 0);
      }
    }
    __syncthreads();
  }

  const int rb = row0 + w * 16 + lg * 4;
#pragma unroll
  for (int nf = 0; nf < 16; ++nf) {
    const int col = nf * 16 + lm;
    const float bv = bias[col];
#pragma unroll
    for (int j = 0; j < 4; ++j)
      C[(size_t)(rb + j) * 256 + col] = __float2bfloat16(acc[nf][j] + bv);
  }
}

// ---------------------------------------------------------------------------
// Fused per-query pipeline (R12 structure, single-round occupancy).
// 512 threads, 16 queries. LDS 40.9 KB = s_u(union hidden/sampled) 16K +
// s_off 16K (h-swizzled) + s_lg 8K. launch_bounds(512,6): 6 waves/SIMD ->
// 3 blocks/CU -> 768-block capacity -> the 600-block grid runs in ONE round.
// VGPR cap 85 >= R12's natural 80 -> no spill (R14's (512,4)=64 spilled).
// Softmax in registers (w[16], computed x4 redundantly — cheap, keeps ph2
// tap loop LDS-light). s_off XOR-swizzle kills the 16-way h-conflict.
// ---------------------------------------------------------------------------
#define QPB 16

__global__ __launch_bounds__(512, 6) void fused_query_kernel(
    const float* __restrict__ hidden, const __hip_bfloat16* __restrict__ value,
    const float* __restrict__ refpts,
    const float* __restrict__ W_off, const float* __restrict__ b_off,
    const float* __restrict__ W_attn, const float* __restrict__ b_attn,
    const float* __restrict__ W_out, const float* __restrict__ b_out,
    float* __restrict__ out) {
  __shared__ float s_u[QPB][256];     // ph0-1: hidden; ph2-3: sampled
  __shared__ float s_off[QPB][256];   // swizzled: col ^ ((col>>5)<<2)
  __shared__ float s_lg[QPB][128];

  const int nb = gridDim.x;   // 600, divisible by 8
  const int bswz = (blockIdx.x % 8) * (nb / 8) + blockIdx.x / 8;
  const int bq0 = bswz * QPB;
  const int t = threadIdx.x;

  // Phase 0: stage hidden rows
#pragma unroll
  for (int i = 0; i < QPB * 256 / 512; ++i) {
    int idx = i * 512 + t;
    s_u[idx >> 8][idx & 255] = hidden[(size_t)bq0 * 256 + idx];
  }
  __syncthreads();

  // Phase 1: off (thr 0-255: 4 cols x 4 q) | attn (thr 256-511: 4 cols x 2 q)
  if (t < 256) {
    const int cg = t & 63;           // cols cg*4 .. cg*4+3
    const int qg = t >> 6;           // queries qg*4 .. qg*4+3
    float acc[4][4];
#pragma unroll
    for (int j = 0; j < 4; ++j)
#pragma unroll
      for (int c = 0; c < 4; ++c) acc[j][c] = 0.f;
    for (int k0 = 0; k0 < 256; k0 += 4) {
      float4 wv[4];
#pragma unroll
      for (int u = 0; u < 4; ++u)
        wv[u] = *reinterpret_cast<const float4*>(W_off + (size_t)(k0 + u) * 256 + cg * 4);
#pragma unroll
      for (int j = 0; j < 4; ++j) {
        const float4 hv = *reinterpret_cast<const float4*>(&s_u[qg * 4 + j][k0]);
#pragma unroll
        for (int c = 0; c < 4; ++c)
          acc[j][c] += hv.x * (&wv[0].x)[c] + hv.y * (&wv[1].x)[c] +
                       hv.z * (&wv[2].x)[c] + hv.w * (&wv[3].x)[c];
      }
    }
    const float4 bo = *reinterpret_cast<const float4*>(b_off + cg * 4);
    const int scol = (cg * 4) ^ ((cg >> 3) << 2);   // h-swizzle (bits 2-4)
#pragma unroll
    for (int j = 0; j < 4; ++j) {
      float4 r = make_float4(acc[j][0] + bo.x, acc[j][1] + bo.y,
                             acc[j][2] + bo.z, acc[j][3] + bo.w);
      *reinterpret_cast<float4*>(&s_off[qg * 4 + j][scol]) = r;
    }
  } else {
    const int u2 = t - 256;
    const int cg = u2 & 31;          // cols cg*4 .. cg*4+3 (of 128)
    const int qg = u2 >> 5;          // queries qg*2, qg*2+1
    float acc[2][4];
#pragma unroll
    for (int j = 0; j < 2; ++j)
#pragma unroll
      for (int c = 0; c < 4; ++c) acc[j][c] = 0.f;
    for (int k0 = 0; k0 < 256; k0 += 4) {
      float4 wv[4];
#pragma unroll
      for (int u = 0; u < 4; ++u)
        wv[u] = *reinterpret_cast<const float4*>(W_attn + (size_t)(k0 + u) * 128 + cg * 4);
#pragma unroll
      for (int j = 0; j < 2; ++j) {
        const float4 hv = *reinterpret_cast<const float4*>(&s_u[qg * 2 + j][k0]);
#pragma unroll
        for (int c = 0; c < 4; ++c)
          acc[j][c] += hv.x * (&wv[0].x)[c] + hv.y * (&wv[1].x)[c] +
                       hv.z * (&wv[2].x)[c] + hv.w * (&wv[3].x)[c];
      }
    }
    const float4 ba = *reinterpret_cast<const float4*>(b_attn + cg * 4);
#pragma unroll
    for (int j = 0; j < 2; ++j) {
      float4 r = make_float4(acc[j][0] + ba.x, acc[j][1] + ba.y,
                             acc[j][2] + ba.z, acc[j][3] + ba.w);
      *reinterpret_cast<float4*>(&s_lg[qg * 2 + j][cg * 4]) = r;
    }
  }
  __syncthreads();

  // Phase 2: softmax (registers, x4 redundant) + bilinear sampling
  {
    const int q = t >> 5;       // 0..15
    const int sub = t & 31;
    const int h = sub >> 2;
    const int c4 = sub & 3;
    const int bq = bq0 + q;
    const int b = bq / QQ;

    const float4 ref = *reinterpret_cast<const float4*>(refpts + (size_t)bq * 4);

    float w[16];
    {
      const float* lg = &s_lg[q][h * 16];
      float m = lg[0];
#pragma unroll
      for (int j = 1; j < 16; ++j) m = fmaxf(m, lg[j]);
      float s = 0.f;
#pragma unroll
      for (int j = 0; j < 16; ++j) { w[j] = __expf(lg[j] - m); s += w[j]; }
      float inv = 1.f / s;
#pragma unroll
      for (int j = 0; j < 16; ++j) w[j] *= inv;
    }

    const float rx = ref.x, ry = ref.y, rw = ref.z, rh = ref.w;
    const unsigned short* vb =
        (const unsigned short*)value + (size_t)b * SS * DD + h * DHH + c4 * 8;

    float acc[8];
#pragma unroll
    for (int j = 0; j < 8; ++j) acc[j] = 0.f;

    const int dims[4] = {80, 40, 20, 10};
    const int sts[4] = {0, 6400, 8000, 8400};
    const int hsw = h << 2;     // s_off un-swizzle mask for this head

#pragma unroll
    for (int l = 0; l < LL; ++l) {
      const int dim = dims[l];
      const int st = sts[l];
      const float fdim = (float)dim;
#pragma unroll
      for (int p = 0; p < PP; ++p) {
        const int tapi = l * 4 + p;
        const int oi = (h * 16 + tapi) * 2;
        const float2 oxy = *reinterpret_cast<const float2*>(&s_off[q][oi ^ hsw]);
        const float locx = rx + oxy.x * rw * 0.125f;
        const float locy = ry + oxy.y * rh * 0.125f;
        const float x = locx * fdim - 0.5f;
        const float y = locy * fdim - 0.5f;
        const float x0f = floorf(x), y0f = floorf(y);
        const float fx = x - x0f, fy = y - y0f;
        const int x0 = (int)x0f, y0 = (int)y0f;
        const float wt = w[tapi];
        const float bw[4] = {(1.f - fx) * (1.f - fy), fx * (1.f - fy),
                             (1.f - fx) * fy, fx * fy};
        const int cx[4] = {x0, x0 + 1, x0, x0 + 1};
        const int cy[4] = {y0, y0, y0 + 1, y0 + 1};
#pragma unroll
        for (int c = 0; c < 4; ++c) {
          const int xi = cx[c], yi = cy[c];
          const bool valid = (xi >= 0) & (xi < dim) & (yi >= 0) & (yi < dim);
          const int xc = min(max(xi, 0), dim - 1);
          const int yc = min(max(yi, 0), dim - 1);
          const uint4 v = *reinterpret_cast<const uint4*>(
              vb + (size_t)(st + yc * dim + xc) * DD);
          const float wv = valid ? bw[c] * wt : 0.f;
          const unsigned u[4] = {v.x, v.y, v.z, v.w};
#pragma unroll
          for (int k = 0; k < 4; ++k) {
            const float lo = __builtin_bit_cast(float, u[k] << 16);
            const float hi = __builtin_bit_cast(float, u[k] & 0xFFFF0000u);
            acc[2 * k] += lo * wv;
            acc[2 * k + 1] += hi * wv;
          }
        }
      }
    }
    // s_u last read in ph1 (behind the barrier) — safe to overwrite now
#pragma unroll
    for (int j = 0; j < 8; ++j) s_u[q][h * DHH + c4 * 8 + j] = acc[j];
  }
  __syncthreads();

  // Phase 3: out = samp @ W_out + b_out (all threads: 4 cols x 2 q)
  {
    const int cg = t & 63;           // cols cg*4 .. cg*4+3
    const int qg = t >> 6;           // queries qg*2, qg*2+1
    float acc[2][4];
#pragma unroll
    for (int j = 0; j < 2; ++j)
#pragma unroll
      for (int c = 0; c < 4; ++c) acc[j][c] = 0.f;
    for (int k0 = 0; k0 < 256; k0 += 4) {
      float4 wv[4];
#pragma unroll
      for (int u = 0; u < 4; ++u)
        wv[u] = *reinterpret_cast<const float4*>(W_out + (size_t)(k0 + u) * 256 + cg * 4);
#pragma unroll
      for (int j = 0; j < 2; ++j) {
        const float4 sv = *reinterpret_cast<const float4*>(&s_u[qg * 2 + j][k0]);
#pragma unroll
        for (int c = 0; c < 4; ++c)
          acc[j][c] += sv.x * (&wv[0].x)[c] + sv.y * (&wv[1].x)[c] +
                       sv.z * (&wv[2].x)[c] + sv.w * (&wv[3].x)[c];
      }
    }
    const float4 bu = *reinterpret_cast<const float4*>(b_out + cg * 4);
#pragma unroll
    for (int j = 0; j < 2; ++j) {
      float4 r = make_float4(acc[j][0] + bu.x, acc[j][1] + bu.y,
                             acc[j][2] + bu.z, acc[j][3] + bu.w);
      *reinterpret_cast<float4*>(out + (size_t)(bq0 + qg * 2 + j) * 256 + cg * 4) = r;
    }
  }
}

// ---------------------------------------------------------------------------
// Launch
// ---------------------------------------------------------------------------
extern "C" void kernel_launch(void* const* d_in, const int* in_sizes, int n_in,
                              void* d_out, int out_size, void* d_ws, size_t ws_size,
                              hipStream_t stream) {
  const float* hidden = (const float*)d_in[0];
  const float* ehs    = (const float*)d_in[1];
  const float* refpts = (const float*)d_in[2];
  const float* W_val  = (const float*)d_in[3];
  const float* b_val  = (const float*)d_in[4];
  const float* W_off  = (const float*)d_in[5];
  const float* b_off  = (const float*)d_in[6];
  const float* W_attn = (const float*)d_in[7];
  const float* b_attn = (const float*)d_in[8];
  const float* W_out  = (const float*)d_in[9];
  const float* b_out  = (const float*)d_in[10];
  float* out = (float*)d_out;

  // Workspace layout
  char* ws = (char*)d_ws;
  __hip_bfloat16* value = (__hip_bfloat16*)ws;                 // 139,264,000 B
  unsigned short* wbfS = (unsigned short*)(ws + 139264000);    // 131,072 B

  const int M_val = BB * SS;   // 272000
  const int M_q   = BB * QQ;   // 9600

  // 0. W_val -> bf16 [n][k], XOR-swizzled
  wcvt_kernel<<<256, 256, 0, stream>>>(W_val, wbfS);
  // 1. value = ehs @ W_val + b_val  (bf16 MFMA)
  gemm_val_mfma<<<M_val / 64, 256, 0, stream>>>(ehs, wbfS, b_val, value);
  // 2. fused: off/attn projections + softmax + sampling + out projection
  fused_query_kernel<<<M_q / QPB, 512, 0, stream>>>(
      hidden, value, refpts, W_off, b_off, W_attn, b_attn, W_out, b_out, out);
}

// Round 16
// 435.307 us; speedup vs baseline: 1.0001x; 1.0001x over previous
//
#include <hip/hip_runtime.h>
#include <hip/hip_bf16.h>

// Problem constants
#define BB 32
#define QQ 300
#define DD 256
#define HH 8
#define DHH 32
#define LL 4
#define PP 4
#define SS 8500

typedef __attribute__((ext_vector_type(8))) short bf16x8;
typedef __attribute__((ext_vector_type(4))) float f32x4;

__device__ inline unsigned short f2bf(float f) {
  unsigned int u = __builtin_bit_cast(unsigned int, f);
  unsigned int r = (u + 0x7FFFu + ((u >> 16) & 1u)) >> 16;
  return (unsigned short)r;
}

// ---------------------------------------------------------------------------
// Convert W_val (256x256 f32, [k][n]) -> bf16 [n][k] with T2 XOR swizzle
// ---------------------------------------------------------------------------
__global__ __launch_bounds__(256) void wcvt_kernel(const float* __restrict__ W,
                                                   unsigned short* __restrict__ wbfS) {
  int t = blockIdx.x * 256 + threadIdx.x;   // 0..65535
  int k = t >> 8, n = t & 255;              // coalesced read of W[k][*]
  wbfS[n * 256 + (k ^ ((n & 7) << 3))] = f2bf(W[(size_t)k * 256 + n]);
}

// ---------------------------------------------------------------------------
// Value GEMM (unchanged — 4 blocks/CU, ~4.9 TB/s effective):
// C[M x 256] = bf16(A[M x 256] f32) @ bf16(W) + bias.
// ---------------------------------------------------------------------------
__global__ __launch_bounds__(256, 4) void gemm_val_mfma(
    const float* __restrict__ A, const unsigned short* __restrict__ WbfS,
    const float* __restrict__ bias, __hip_bfloat16* __restrict__ C) {
  __shared__ __align__(16) unsigned short Alds[64 * 64];  // 8 KB, swizzled
  __shared__ __align__(16) unsigned short Blds[256 * 64]; // 32 KB, swizzled

  const int t = threadIdx.x;
  const int lane = t & 63;
  const int w = t >> 6;
  const int lm = lane & 15, lg = lane >> 4;
  const int row0 = blockIdx.x * 64;

  f32x4 acc[16];
#pragma unroll
  for (int nf = 0; nf < 16; ++nf) acc[nf] = {0.f, 0.f, 0.f, 0.f};

  for (int k0 = 0; k0 < 256; k0 += 64) {
#pragma unroll
    for (int i = 0; i < 8; ++i) {
      const unsigned short* gp = WbfS +
          (size_t)(w * 64 + i * 8 + (lane >> 3)) * 256 + k0 + (lane & 7) * 8;
      unsigned char* lp = reinterpret_cast<unsigned char*>(Blds) + (w * 8 + i) * 1024;
      __builtin_amdgcn_global_load_lds(
          (const __attribute__((address_space(1))) void*)gp,
          (__attribute__((address_space(3))) void*)lp, 16, 0, 0);
    }
#pragma unroll
    for (int i = 0; i < 4; ++i) {
      int u = i * 256 + t;
      int r = u >> 4, c4 = (u & 15) * 4;
      float4 v = *reinterpret_cast<const float4*>(A + (size_t)(row0 + r) * 256 + k0 + c4);
      ushort4 h;
      h.x = f2bf(v.x); h.y = f2bf(v.y); h.z = f2bf(v.z); h.w = f2bf(v.w);
      *reinterpret_cast<ushort4*>(&Alds[r * 64 + (c4 ^ ((r & 7) << 3))]) = h;
    }
    __syncthreads();

#pragma unroll
    for (int ks = 0; ks < 2; ++ks) {
      const int kk = (ks * 32 + lg * 8) ^ ((lm & 7) << 3);
      const bf16x8 af = *reinterpret_cast<const bf16x8*>(&Alds[(w * 16 + lm) * 64 + kk]);
#pragma unroll
      for (int nf = 0; nf < 16; ++nf) {
        const bf16x8 bfr = *reinterpret_cast<const bf16x8*>(&Blds[(nf * 16 + lm) * 64 + kk]);
        acc[nf] = __builtin_amdgcn_mfma_f32_16x16x32_bf16(af, bfr, acc[nf], 0, 0, 0);
      }
    }
    __syncthreads();
  }

  const int rb = row0 + w * 16 + lg * 4;
#pragma unroll
  for (int nf = 0; nf < 16; ++nf) {
    const int col = nf * 16 + lm;
    const float bv = bias[col];
#pragma unroll
    for (int j = 0; j < 4; ++j)
      C[(size_t)(rb + j) * 256 + col] = __float2bfloat16(acc[nf][j] + bv);
  }
}

// ---------------------------------------------------------------------------
// Fused per-query pipeline (R12 structure, single-round occupancy).
// 512 threads, 16 queries. LDS 40.9 KB = s_u(union hidden/sampled) 16K +
// s_off 16K (h-swizzled) + s_lg 8K. launch_bounds(512,6): 6 waves/SIMD ->
// 3 blocks/CU -> 768-block capacity -> the 600-block grid runs in ONE round.
// VGPR cap 85 >= R12's natural 80 -> no spill (R14's (512,4)=64 spilled).
// Softmax in registers (w[16], computed x4 redundantly — cheap, keeps ph2
// tap loop LDS-light). s_off XOR-swizzle kills the 16-way h-conflict.
// ---------------------------------------------------------------------------
#define QPB 16

__global__ __launch_bounds__(512, 6) void fused_query_kernel(
    const float* __restrict__ hidden, const __hip_bfloat16* __restrict__ value,
    const float* __restrict__ refpts,
    const float* __restrict__ W_off, const float* __restrict__ b_off,
    const float* __restrict__ W_attn, const float* __restrict__ b_attn,
    const float* __restrict__ W_out, const float* __restrict__ b_out,
    float* __restrict__ out) {
  __shared__ float s_u[QPB][256];     // ph0-1: hidden; ph2-3: sampled
  __shared__ float s_off[QPB][256];   // swizzled: col ^ ((col>>5)<<2)
  __shared__ float s_lg[QPB][128];

  const int nb = gridDim.x;   // 600, divisible by 8
  const int bswz = (blockIdx.x % 8) * (nb / 8) + blockIdx.x / 8;
  const int bq0 = bswz * QPB;
  const int t = threadIdx.x;

  // Phase 0: stage hidden rows
#pragma unroll
  for (int i = 0; i < QPB * 256 / 512; ++i) {
    int idx = i * 512 + t;
    s_u[idx >> 8][idx & 255] = hidden[(size_t)bq0 * 256 + idx];
  }
  __syncthreads();

  // Phase 1: off (thr 0-255: 4 cols x 4 q) | attn (thr 256-511: 4 cols x 2 q)
  if (t < 256) {
    const int cg = t & 63;           // cols cg*4 .. cg*4+3
    const int qg = t >> 6;           // queries qg*4 .. qg*4+3
    float acc[4][4];
#pragma unroll
    for (int j = 0; j < 4; ++j)
#pragma unroll
      for (int c = 0; c < 4; ++c) acc[j][c] = 0.f;
    for (int k0 = 0; k0 < 256; k0 += 4) {
      float4 wv[4];
#pragma unroll
      for (int u = 0; u < 4; ++u)
        wv[u] = *reinterpret_cast<const float4*>(W_off + (size_t)(k0 + u) * 256 + cg * 4);
#pragma unroll
      for (int j = 0; j < 4; ++j) {
        const float4 hv = *reinterpret_cast<const float4*>(&s_u[qg * 4 + j][k0]);
#pragma unroll
        for (int c = 0; c < 4; ++c)
          acc[j][c] += hv.x * (&wv[0].x)[c] + hv.y * (&wv[1].x)[c] +
                       hv.z * (&wv[2].x)[c] + hv.w * (&wv[3].x)[c];
      }
    }
    const float4 bo = *reinterpret_cast<const float4*>(b_off + cg * 4);
    const int scol = (cg * 4) ^ ((cg >> 3) << 2);   // h-swizzle (bits 2-4)
#pragma unroll
    for (int j = 0; j < 4; ++j) {
      float4 r = make_float4(acc[j][0] + bo.x, acc[j][1] + bo.y,
                             acc[j][2] + bo.z, acc[j][3] + bo.w);
      *reinterpret_cast<float4*>(&s_off[qg * 4 + j][scol]) = r;
    }
  } else {
    const int u2 = t - 256;
    const int cg = u2 & 31;          // cols cg*4 .. cg*4+3 (of 128)
    const int qg = u2 >> 5;          // queries qg*2, qg*2+1
    float acc[2][4];
#pragma unroll
    for (int j = 0; j < 2; ++j)
#pragma unroll
      for (int c = 0; c < 4; ++c) acc[j][c] = 0.f;
    for (int k0 = 0; k0 < 256; k0 += 4) {
      float4 wv[4];
#pragma unroll
      for (int u = 0; u < 4; ++u)
        wv[u] = *reinterpret_cast<const float4*>(W_attn + (size_t)(k0 + u) * 128 + cg * 4);
#pragma unroll
      for (int j = 0; j < 2; ++j) {
        const float4 hv = *reinterpret_cast<const float4*>(&s_u[qg * 2 + j][k0]);
#pragma unroll
        for (int c = 0; c < 4; ++c)
          acc[j][c] += hv.x * (&wv[0].x)[c] + hv.y * (&wv[1].x)[c] +
                       hv.z * (&wv[2].x)[c] + hv.w * (&wv[3].x)[c];
      }
    }
    const float4 ba = *reinterpret_cast<const float4*>(b_attn + cg * 4);
#pragma unroll
    for (int j = 0; j < 2; ++j) {
      float4 r = make_float4(acc[j][0] + ba.x, acc[j][1] + ba.y,
                             acc[j][2] + ba.z, acc[j][3] + ba.w);
      *reinterpret_cast<float4*>(&s_lg[qg * 2 + j][cg * 4]) = r;
    }
  }
  __syncthreads();

  // Phase 2: softmax (registers, x4 redundant) + bilinear sampling
  {
    const int q = t >> 5;       // 0..15
    const int sub = t & 31;
    const int h = sub >> 2;
    const int c4 = sub & 3;
    const int bq = bq0 + q;
    const int b = bq / QQ;

    const float4 ref = *reinterpret_cast<const float4*>(refpts + (size_t)bq * 4);

    float w[16];
    {
      const float* lg = &s_lg[q][h * 16];
      float m = lg[0];
#pragma unroll
      for (int j = 1; j < 16; ++j) m = fmaxf(m, lg[j]);
      float s = 0.f;
#pragma unroll
      for (int j = 0; j < 16; ++j) { w[j] = __expf(lg[j] - m); s += w[j]; }
      float inv = 1.f / s;
#pragma unroll
      for (int j = 0; j < 16; ++j) w[j] *= inv;
    }

    const float rx = ref.x, ry = ref.y, rw = ref.z, rh = ref.w;
    const unsigned short* vb =
        (const unsigned short*)value + (size_t)b * SS * DD + h * DHH + c4 * 8;

    float acc[8];
#pragma unroll
    for (int j = 0; j < 8; ++j) acc[j] = 0.f;

    const int dims[4] = {80, 40, 20, 10};
    const int sts[4] = {0, 6400, 8000, 8400};
    const int hsw = h << 2;     // s_off un-swizzle mask for this head

#pragma unroll
    for (int l = 0; l < LL; ++l) {
      const int dim = dims[l];
      const int st = sts[l];
      const float fdim = (float)dim;
#pragma unroll
      for (int p = 0; p < PP; ++p) {
        const int tapi = l * 4 + p;
        const int oi = (h * 16 + tapi) * 2;
        const float2 oxy = *reinterpret_cast<const float2*>(&s_off[q][oi ^ hsw]);
        const float locx = rx + oxy.x * rw * 0.125f;
        const float locy = ry + oxy.y * rh * 0.125f;
        const float x = locx * fdim - 0.5f;
        const float y = locy * fdim - 0.5f;
        const float x0f = floorf(x), y0f = floorf(y);
        const float fx = x - x0f, fy = y - y0f;
        const int x0 = (int)x0f, y0 = (int)y0f;
        const float wt = w[tapi];
        const float bw[4] = {(1.f - fx) * (1.f - fy), fx * (1.f - fy),
                             (1.f - fx) * fy, fx * fy};
        const int cx[4] = {x0, x0 + 1, x0, x0 + 1};
        const int cy[4] = {y0, y0, y0 + 1, y0 + 1};
#pragma unroll
        for (int c = 0; c < 4; ++c) {
          const int xi = cx[c], yi = cy[c];
          const bool valid = (xi >= 0) & (xi < dim) & (yi >= 0) & (yi < dim);
          const int xc = min(max(xi, 0), dim - 1);
          const int yc = min(max(yi, 0), dim - 1);
          const uint4 v = *reinterpret_cast<const uint4*>(
              vb + (size_t)(st + yc * dim + xc) * DD);
          const float wv = valid ? bw[c] * wt : 0.f;
          const unsigned u[4] = {v.x, v.y, v.z, v.w};
#pragma unroll
          for (int k = 0; k < 4; ++k) {
            const float lo = __builtin_bit_cast(float, u[k] << 16);
            const float hi = __builtin_bit_cast(float, u[k] & 0xFFFF0000u);
            acc[2 * k] += lo * wv;
            acc[2 * k + 1] += hi * wv;
          }
        }
      }
    }
    // s_u last read in ph1 (behind the barrier) — safe to overwrite now
#pragma unroll
    for (int j = 0; j < 8; ++j) s_u[q][h * DHH + c4 * 8 + j] = acc[j];
  }
  __syncthreads();

  // Phase 3: out = samp @ W_out + b_out (all threads: 4 cols x 2 q)
  {
    const int cg = t & 63;           // cols cg*4 .. cg*4+3
    const int qg = t >> 6;           // queries qg*2, qg*2+1
    float acc[2][4];
#pragma unroll
    for (int j = 0; j < 2; ++j)
#pragma unroll
      for (int c = 0; c < 4; ++c) acc[j][c] = 0.f;
    for (int k0 = 0; k0 < 256; k0 += 4) {
      float4 wv[4];
#pragma unroll
      for (int u = 0; u < 4; ++u)
        wv[u] = *reinterpret_cast<const float4*>(W_out + (size_t)(k0 + u) * 256 + cg * 4);
#pragma unroll
      for (int j = 0; j < 2; ++j) {
        const float4 sv = *reinterpret_cast<const float4*>(&s_u[qg * 2 + j][k0]);
#pragma unroll
        for (int c = 0; c < 4; ++c)
          acc[j][c] += sv.x * (&wv[0].x)[c] + sv.y * (&wv[1].x)[c] +
                       sv.z * (&wv[2].x)[c] + sv.w * (&wv[3].x)[c];
      }
    }
    const float4 bu = *reinterpret_cast<const float4*>(b_out + cg * 4);
#pragma unroll
    for (int j = 0; j < 2; ++j) {
      float4 r = make_float4(acc[j][0] + bu.x, acc[j][1] + bu.y,
                             acc[j][2] + bu.z, acc[j][3] + bu.w);
      *reinterpret_cast<float4*>(out + (size_t)(bq0 + qg * 2 + j) * 256 + cg * 4) = r;
    }
  }
}

// ---------------------------------------------------------------------------
// Launch
// ---------------------------------------------------------------------------
extern "C" void kernel_launch(void* const* d_in, const int* in_sizes, int n_in,
                              void* d_out, int out_size, void* d_ws, size_t ws_size,
                              hipStream_t stream) {
  const float* hidden = (const float*)d_in[0];
  const float* ehs    = (const float*)d_in[1];
  const float* refpts = (const float*)d_in[2];
  const float* W_val  = (const float*)d_in[3];
  const float* b_val  = (const float*)d_in[4];
  const float* W_off  = (const float*)d_in[5];
  const float* b_off  = (const float*)d_in[6];
  const float* W_attn = (const float*)d_in[7];
  const float* b_attn = (const float*)d_in[8];
  const float* W_out  = (const float*)d_in[9];
  const float* b_out  = (const float*)d_in[10];
  float* out = (float*)d_out;

  // Workspace layout
  char* ws = (char*)d_ws;
  __hip_bfloat16* value = (__hip_bfloat16*)ws;                 // 139,264,000 B
  unsigned short* wbfS = (unsigned short*)(ws + 139264000);    // 131,072 B

  const int M_val = BB * SS;   // 272000
  const int M_q   = BB * QQ;   // 9600

  // 0. W_val -> bf16 [n][k], XOR-swizzled
  wcvt_kernel<<<256, 256, 0, stream>>>(W_val, wbfS);
  // 1. value = ehs @ W_val + b_val  (bf16 MFMA)
  gemm_val_mfma<<<M_val / 64, 256, 0, stream>>>(ehs, wbfS, b_val, value);
  // 2. fused: off/attn projections + softmax + sampling + out projection
  fused_query_kernel<<<M_q / QPB, 512, 0, stream>>>(
      hidden, value, refpts, W_off, b_off, W_attn, b_attn, W_out, b_out, out);
}

// Round 17
// 195.844 us; speedup vs baseline: 2.2230x; 2.2227x over previous
//
#include <hip/hip_runtime.h>
#include <hip/hip_bf16.h>

// Problem constants
#define BB 32
#define QQ 300
#define DD 256
#define HH 8
#define DHH 32
#define LL 4
#define PP 4
#define SS 8500

typedef __attribute__((ext_vector_type(8))) short bf16x8;
typedef __attribute__((ext_vector_type(8))) _Float16 f16x8;
typedef __attribute__((ext_vector_type(4))) float f32x4;

__device__ inline unsigned short f2bf(float f) {
  unsigned int u = __builtin_bit_cast(unsigned int, f);
  unsigned int r = (u + 0x7FFFu + ((u >> 16) & 1u)) >> 16;
  return (unsigned short)r;
}
__device__ inline unsigned short f2h(float f) {
  return __builtin_bit_cast(unsigned short, (_Float16)f);
}
__device__ inline float h2f(unsigned short u) {
  return (float)__builtin_bit_cast(_Float16, u);
}

// ---------------------------------------------------------------------------
// W (256x256 f32 [k][n]) -> bf16 [n][256] with XOR swizzle (per 64-k window).
// Used for W_val and W_out.
// ---------------------------------------------------------------------------
__global__ __launch_bounds__(256) void wcvt_kernel(const float* __restrict__ W,
                                                   unsigned short* __restrict__ dst) {
  int t = blockIdx.x * 256 + threadIdx.x;   // 0..65535
  int k = t >> 8, n = t & 255;              // coalesced read of W[k][*]
  dst[n * 256 + (k ^ ((n & 7) << 3))] = f2bf(W[(size_t)k * 256 + n]);
}

// ---------------------------------------------------------------------------
// W (256xN f32 [k][n]) -> f16 split [n][512]: k 0-255 = hi, 256-511 = lo,
// swizzled per 64-k window. LDS tile transpose for coalescing.
// ---------------------------------------------------------------------------
template <int N>
__global__ __launch_bounds__(256) void wextf16_kernel(const float* __restrict__ W,
                                                      unsigned short* __restrict__ dst) {
  __shared__ float s_w[64][65];
  constexpr int NT = N / 64;
  const int kt = blockIdx.x / NT;       // k-tile 0..3
  const int nt = blockIdx.x % NT;       // n-tile
  const int t = threadIdx.x;
#pragma unroll
  for (int i = 0; i < 16; ++i) {
    int idx = i * 256 + t;
    int kk = idx >> 6, nn = idx & 63;
    s_w[kk][nn] = W[(size_t)(kt * 64 + kk) * N + nt * 64 + nn];
  }
  __syncthreads();
#pragma unroll
  for (int i = 0; i < 16; ++i) {
    int idx = i * 256 + t;
    int nn = idx >> 6, kk = idx & 63;
    const int n = nt * 64 + nn;
    const float v = s_w[kk][nn];
    const unsigned short hi = f2h(v);
    const unsigned short lo = f2h(v - h2f(hi));
    const int ksw = kt * 64 + (kk ^ ((n & 7) << 3));
    dst[(size_t)n * 512 + ksw] = hi;
    dst[(size_t)n * 512 + 256 + ksw] = lo;
  }
}

// ---------------------------------------------------------------------------
// hidden (9600x256 f32) -> f16 [m][256], swizzled per 64-k window.
// ---------------------------------------------------------------------------
__global__ __launch_bounds__(256) void hidh_kernel(const float* __restrict__ hidden,
                                                   unsigned short* __restrict__ hidh) {
  int t = blockIdx.x * 256 + threadIdx.x;    // 9600*64 units
  int m = t >> 6, j = (t & 63) * 4;
  float4 v = *reinterpret_cast<const float4*>(hidden + (size_t)m * 256 + j);
  ushort4 h;
  h.x = f2h(v.x); h.y = f2h(v.y); h.z = f2h(v.z); h.w = f2h(v.w);
  *reinterpret_cast<ushort4*>(hidh + (size_t)m * 256 + (j ^ ((m & 7) << 3))) = h;
}

// ---------------------------------------------------------------------------
// Value GEMM (unchanged, proven ~85 us, 4 blocks/CU).
// ---------------------------------------------------------------------------
__global__ __launch_bounds__(256, 4) void gemm_val_mfma(
    const float* __restrict__ A, const unsigned short* __restrict__ WbfS,
    const float* __restrict__ bias, __hip_bfloat16* __restrict__ C) {
  __shared__ __align__(16) unsigned short Alds[64 * 64];
  __shared__ __align__(16) unsigned short Blds[256 * 64];

  const int t = threadIdx.x;
  const int lane = t & 63;
  const int w = t >> 6;
  const int lm = lane & 15, lg = lane >> 4;
  const int row0 = blockIdx.x * 64;

  f32x4 acc[16];
#pragma unroll
  for (int nf = 0; nf < 16; ++nf) acc[nf] = {0.f, 0.f, 0.f, 0.f};

  for (int k0 = 0; k0 < 256; k0 += 64) {
#pragma unroll
    for (int i = 0; i < 8; ++i) {
      const unsigned short* gp = WbfS +
          (size_t)(w * 64 + i * 8 + (lane >> 3)) * 256 + k0 + (lane & 7) * 8;
      unsigned char* lp = reinterpret_cast<unsigned char*>(Blds) + (w * 8 + i) * 1024;
      __builtin_amdgcn_global_load_lds(
          (const __attribute__((address_space(1))) void*)gp,
          (__attribute__((address_space(3))) void*)lp, 16, 0, 0);
    }
#pragma unroll
    for (int i = 0; i < 4; ++i) {
      int u = i * 256 + t;
      int r = u >> 4, c4 = (u & 15) * 4;
      float4 v = *reinterpret_cast<const float4*>(A + (size_t)(row0 + r) * 256 + k0 + c4);
      ushort4 h;
      h.x = f2bf(v.x); h.y = f2bf(v.y); h.z = f2bf(v.z); h.w = f2bf(v.w);
      *reinterpret_cast<ushort4*>(&Alds[r * 64 + (c4 ^ ((r & 7) << 3))]) = h;
    }
    __syncthreads();

#pragma unroll
    for (int ks = 0; ks < 2; ++ks) {
      const int kk = (ks * 32 + lg * 8) ^ ((lm & 7) << 3);
      const bf16x8 af = *reinterpret_cast<const bf16x8*>(&Alds[(w * 16 + lm) * 64 + kk]);
#pragma unroll
      for (int nf = 0; nf < 16; ++nf) {
        const bf16x8 bfr = *reinterpret_cast<const bf16x8*>(&Blds[(nf * 16 + lm) * 64 + kk]);
        acc[nf] = __builtin_amdgcn_mfma_f32_16x16x32_bf16(af, bfr, acc[nf], 0, 0, 0);
      }
    }
    __syncthreads();
  }

  const int rb = row0 + w * 16 + lg * 4;
#pragma unroll
  for (int nf = 0; nf < 16; ++nf) {
    const int col = nf * 16 + lm;
    const float bv = bias[col];
#pragma unroll
    for (int j = 0; j < 4; ++j)
      C[(size_t)(rb + j) * 256 + col] = __float2bfloat16(acc[nf][j] + bv);
  }
}

// ---------------------------------------------------------------------------
// Generic MFMA GEMM: C[M x N] f32 = A[M x KA] @ B[N x KB] + bias.
// A, B pre-swizzled 16-bit (f16 or bf16) in memory; both staged via
// global_load_lds. A k-index = k0 & (KA-1) (W-side split without A dup).
// 256 threads / 4 waves; BM=64; wave = 16 rows x N cols.
// ---------------------------------------------------------------------------
template <int KB, int KA, int N, bool F16>
__global__ __launch_bounds__(256) void gemm_tpl(
    const unsigned short* __restrict__ A, const unsigned short* __restrict__ B,
    const float* __restrict__ bias, float* __restrict__ C) {
  __shared__ __align__(16) unsigned short Alds[64 * 64];
  __shared__ __align__(16) unsigned short Blds[N * 64];

  const int t = threadIdx.x;
  const int lane = t & 63;
  const int w = t >> 6;
  const int lm = lane & 15, lg = lane >> 4;
  const int row0 = blockIdx.x * 64;
  constexpr int NF = N / 16;

  f32x4 acc[NF];
#pragma unroll
  for (int nf = 0; nf < NF; ++nf) acc[nf] = {0.f, 0.f, 0.f, 0.f};

  for (int k0 = 0; k0 < KB; k0 += 64) {
    const int ka = k0 & (KA - 1);
#pragma unroll
    for (int i = 0; i < N / 32; ++i) {
      const int c = w * (N / 32) + i;
      const unsigned short* gp = B + (size_t)(c * 8 + (lane >> 3)) * KB + k0 + (lane & 7) * 8;
      unsigned char* lp = reinterpret_cast<unsigned char*>(Blds) + c * 1024;
      __builtin_amdgcn_global_load_lds(
          (const __attribute__((address_space(1))) void*)gp,
          (__attribute__((address_space(3))) void*)lp, 16, 0, 0);
    }
#pragma unroll
    for (int i = 0; i < 2; ++i) {
      const int c = w * 2 + i;
      const unsigned short* gp = A + (size_t)(row0 + c * 8 + (lane >> 3)) * KA + ka + (lane & 7) * 8;
      unsigned char* lp = reinterpret_cast<unsigned char*>(Alds) + c * 1024;
      __builtin_amdgcn_global_load_lds(
          (const __attribute__((address_space(1))) void*)gp,
          (__attribute__((address_space(3))) void*)lp, 16, 0, 0);
    }
    __syncthreads();

#pragma unroll
    for (int ks = 0; ks < 2; ++ks) {
      const int kk = (ks * 32 + lg * 8) ^ ((lm & 7) << 3);
      const bf16x8 af = *reinterpret_cast<const bf16x8*>(&Alds[(w * 16 + lm) * 64 + kk]);
#pragma unroll
      for (int nf = 0; nf < NF; ++nf) {
        const bf16x8 bfr = *reinterpret_cast<const bf16x8*>(&Blds[(nf * 16 + lm) * 64 + kk]);
        if constexpr (F16)
          acc[nf] = __builtin_amdgcn_mfma_f32_16x16x32_f16(
              __builtin_bit_cast(f16x8, af), __builtin_bit_cast(f16x8, bfr), acc[nf], 0, 0, 0);
        else
          acc[nf] = __builtin_amdgcn_mfma_f32_16x16x32_bf16(af, bfr, acc[nf], 0, 0, 0);
      }
    }
    __syncthreads();
  }

  const int rb = row0 + w * 16 + lg * 4;
#pragma unroll
  for (int nf = 0; nf < NF; ++nf) {
    const int col = nf * 16 + lm;
    const float bv = bias[col];
#pragma unroll
    for (int j = 0; j < 4; ++j)
      C[(size_t)(rb + j) * N + col] = acc[nf][j] + bv;
  }
}

// ---------------------------------------------------------------------------
// Sampler: stage off/logits -> softmax once per (q,h) -> gather -> samp bf16
// (pre-swizzled for gemm_out). 256 thr, 8 queries, LDS 12 KB -> high occ.
// ---------------------------------------------------------------------------
#define QPB 8

__global__ __launch_bounds__(256) void sample_kernel(
    const __hip_bfloat16* __restrict__ value, const float* __restrict__ offb,
    const float* __restrict__ logits, const float* __restrict__ refpts,
    unsigned short* __restrict__ samp) {
  __shared__ float s_off[QPB][256];   // h-swizzled: col ^ ((col>>5)<<2)
  __shared__ float s_lg[QPB][128];

  const int nb = gridDim.x;   // 1200
  const int bswz = (blockIdx.x % 8) * (nb / 8) + blockIdx.x / 8;
  const int bq0 = bswz * QPB;
  const int t = threadIdx.x;

#pragma unroll
  for (int i = 0; i < QPB; ++i) {
    int idx = i * 256 + t;
    int q = idx >> 8, col = idx & 255;
    s_off[q][col ^ (((col >> 5) & 7) << 2)] = offb[(size_t)bq0 * 256 + idx];
  }
#pragma unroll
  for (int i = 0; i < QPB / 2; ++i) {
    int idx = i * 256 + t;
    s_lg[idx >> 7][idx & 127] = logits[(size_t)bq0 * 128 + idx];
  }
  __syncthreads();

  if (t < QPB * HH) {   // 64 threads: softmax once per (q,h)
    const int q = t >> 3, h = t & 7;
    float* lg = &s_lg[q][h * 16];
    float m = lg[0];
#pragma unroll
    for (int j = 1; j < 16; ++j) m = fmaxf(m, lg[j]);
    float e[16], s = 0.f;
#pragma unroll
    for (int j = 0; j < 16; ++j) { e[j] = __expf(lg[j] - m); s += e[j]; }
    const float inv = 1.f / s;
#pragma unroll
    for (int j = 0; j < 16; ++j) lg[j] = e[j] * inv;
  }
  __syncthreads();

  const int q = t >> 5;
  const int sub = t & 31;
  const int h = sub >> 2;
  const int c4 = sub & 3;
  const int bq = bq0 + q;
  const int b = bq / QQ;

  const float4 ref = *reinterpret_cast<const float4*>(refpts + (size_t)bq * 4);
  const float rx = ref.x, ry = ref.y, rw = ref.z, rh = ref.w;
  const unsigned short* vb =
      (const unsigned short*)value + (size_t)b * SS * DD + h * DHH + c4 * 8;

  float acc[8];
#pragma unroll
  for (int j = 0; j < 8; ++j) acc[j] = 0.f;

  const int dims[4] = {80, 40, 20, 10};
  const int sts[4] = {0, 6400, 8000, 8400};
  const int hsw = h << 2;

#pragma unroll
  for (int l = 0; l < LL; ++l) {
    const int dim = dims[l];
    const int st = sts[l];
    const float fdim = (float)dim;
#pragma unroll
    for (int p = 0; p < PP; ++p) {
      const int tapi = l * 4 + p;
      const float2 oxy =
          *reinterpret_cast<const float2*>(&s_off[q][(h * 32 + 2 * tapi) ^ hsw]);
      const float locx = rx + oxy.x * rw * 0.125f;
      const float locy = ry + oxy.y * rh * 0.125f;
      const float x = locx * fdim - 0.5f;
      const float y = locy * fdim - 0.5f;
      const float x0f = floorf(x), y0f = floorf(y);
      const float fx = x - x0f, fy = y - y0f;
      const int x0 = (int)x0f, y0 = (int)y0f;
      const float wt = s_lg[q][h * 16 + tapi];
      const float bw[4] = {(1.f - fx) * (1.f - fy), fx * (1.f - fy),
                           (1.f - fx) * fy, fx * fy};
      const int cx[4] = {x0, x0 + 1, x0, x0 + 1};
      const int cy[4] = {y0, y0, y0 + 1, y0 + 1};
#pragma unroll
      for (int c = 0; c < 4; ++c) {
        const int xi = cx[c], yi = cy[c];
        const bool valid = (xi >= 0) & (xi < dim) & (yi >= 0) & (yi < dim);
        const int xc = min(max(xi, 0), dim - 1);
        const int yc = min(max(yi, 0), dim - 1);
        const uint4 v = *reinterpret_cast<const uint4*>(
            vb + (size_t)(st + yc * dim + xc) * DD);
        const float wv = valid ? bw[c] * wt : 0.f;
        const unsigned u[4] = {v.x, v.y, v.z, v.w};
#pragma unroll
        for (int k = 0; k < 4; ++k) {
          const float lo = __builtin_bit_cast(float, u[k] << 16);
          const float hi = __builtin_bit_cast(float, u[k] & 0xFFFF0000u);
          acc[2 * k] += lo * wv;
          acc[2 * k + 1] += hi * wv;
        }
      }
    }
  }

  // write samp bf16, pre-swizzled [m][col ^ ((m&7)<<3)] for gemm_out
  bf16x8 o;
#pragma unroll
  for (int j = 0; j < 8; ++j) o[j] = (short)f2bf(acc[j]);
  const int col = (h * DHH + c4 * 8) ^ ((bq & 7) << 3);
  *reinterpret_cast<bf16x8*>(samp + (size_t)bq * 256 + col) = o;
}

// ---------------------------------------------------------------------------
// Launch
// ---------------------------------------------------------------------------
extern "C" void kernel_launch(void* const* d_in, const int* in_sizes, int n_in,
                              void* d_out, int out_size, void* d_ws, size_t ws_size,
                              hipStream_t stream) {
  const float* hidden = (const float*)d_in[0];
  const float* ehs    = (const float*)d_in[1];
  const float* refpts = (const float*)d_in[2];
  const float* W_val  = (const float*)d_in[3];
  const float* b_val  = (const float*)d_in[4];
  const float* W_off  = (const float*)d_in[5];
  const float* b_off  = (const float*)d_in[6];
  const float* W_attn = (const float*)d_in[7];
  const float* b_attn = (const float*)d_in[8];
  const float* W_out  = (const float*)d_in[9];
  const float* b_out  = (const float*)d_in[10];
  float* out = (float*)d_out;

  // Workspace layout (total ~164.5 MB)
  char* ws = (char*)d_ws;
  __hip_bfloat16* value  = (__hip_bfloat16*)ws;                       // 139,264,000
  unsigned short* wvalS  = (unsigned short*)(ws + 139264000);         // 131,072
  unsigned short* woutS  = (unsigned short*)(ws + 139395072);         // 131,072
  unsigned short* woffE  = (unsigned short*)(ws + 139526144);         // 262,144
  unsigned short* wattE  = (unsigned short*)(ws + 139788288);         // 131,072
  unsigned short* hidh   = (unsigned short*)(ws + 139919360);         // 4,915,200
  float*          offb   = (float*)(ws + 144834560);                  // 9,830,400
  float*          logitsb= (float*)(ws + 154664960);                  // 4,915,200
  unsigned short* samp   = (unsigned short*)(ws + 159580160);         // 4,915,200

  const int M_val = BB * SS;   // 272000
  const int M_q   = BB * QQ;   // 9600

  // conversions
  wcvt_kernel<<<256, 256, 0, stream>>>(W_val, wvalS);
  wcvt_kernel<<<256, 256, 0, stream>>>(W_out, woutS);
  wextf16_kernel<256><<<16, 256, 0, stream>>>(W_off, woffE);
  wextf16_kernel<128><<<8, 256, 0, stream>>>(W_attn, wattE);
  hidh_kernel<<<M_q * 64 / 256, 256, 0, stream>>>(hidden, hidh);
  // value projection (bf16 MFMA)
  gemm_val_mfma<<<M_val / 64, 256, 0, stream>>>(ehs, wvalS, b_val, value);
  // off / attn projections (f16 MFMA, W-split K=512)
  gemm_tpl<512, 256, 256, true><<<M_q / 64, 256, 0, stream>>>(hidh, woffE, b_off, offb);
  gemm_tpl<512, 256, 128, true><<<M_q / 64, 256, 0, stream>>>(hidh, wattE, b_attn, logitsb);
  // softmax + bilinear sampling -> samp (bf16, swizzled)
  sample_kernel<<<M_q / QPB, 256, 0, stream>>>(value, offb, logitsb, refpts, samp);
  // out projection (bf16 MFMA)
  gemm_tpl<256, 256, 256, false><<<M_q / 64, 256, 0, stream>>>(samp, woutS, b_out, out);
}

// Round 18
// 194.596 us; speedup vs baseline: 2.2373x; 1.0064x over previous
//
#include <hip/hip_runtime.h>
#include <hip/hip_bf16.h>

// Problem constants
#define BB 32
#define QQ 300
#define DD 256
#define HH 8
#define DHH 32
#define LL 4
#define PP 4
#define SS 8500

typedef __attribute__((ext_vector_type(8))) short bf16x8;
typedef __attribute__((ext_vector_type(8))) _Float16 f16x8;
typedef __attribute__((ext_vector_type(4))) float f32x4;

__device__ inline unsigned short f2bf(float f) {
  unsigned int u = __builtin_bit_cast(unsigned int, f);
  unsigned int r = (u + 0x7FFFu + ((u >> 16) & 1u)) >> 16;
  return (unsigned short)r;
}
__device__ inline unsigned short f2h(float f) {
  return __builtin_bit_cast(unsigned short, (_Float16)f);
}
__device__ inline float h2f(unsigned short u) {
  return (float)__builtin_bit_cast(_Float16, u);
}

// ---------------------------------------------------------------------------
// Merged prep kernel (saves 4 launches):
//   blocks [0,512):   W_val / W_out -> bf16 [n][256] swizzled
//   blocks [512,536): W_off / W_attn -> f16 hi/lo split [n][512] swizzled
//   blocks [536,2936): hidden -> f16 [m][256] swizzled
// ---------------------------------------------------------------------------
__global__ __launch_bounds__(256) void prep_kernel(
    const float* __restrict__ W_val, const float* __restrict__ W_out,
    const float* __restrict__ W_off, const float* __restrict__ W_attn,
    const float* __restrict__ hidden,
    unsigned short* __restrict__ wvalS, unsigned short* __restrict__ woutS,
    unsigned short* __restrict__ woffE, unsigned short* __restrict__ wattE,
    unsigned short* __restrict__ hidh) {
  __shared__ float s_w[64][65];
  const int blk = blockIdx.x;
  const int tid = threadIdx.x;

  if (blk < 512) {
    const float* W = blk < 256 ? W_val : W_out;
    unsigned short* dst = blk < 256 ? wvalS : woutS;
    int t = (blk & 255) * 256 + tid;
    int k = t >> 8, n = t & 255;
    dst[n * 256 + (k ^ ((n & 7) << 3))] = f2bf(W[(size_t)k * 256 + n]);
  } else if (blk < 536) {
    const bool isOff = blk < 528;
    const int N = isOff ? 256 : 128;
    const int NT = N / 64;
    const int lb = isOff ? blk - 512 : blk - 528;
    const float* W = isOff ? W_off : W_attn;
    unsigned short* dst = isOff ? woffE : wattE;
    const int kt = lb / NT, nt = lb % NT;
#pragma unroll
    for (int i = 0; i < 16; ++i) {
      int idx = i * 256 + tid;
      int kk = idx >> 6, nn = idx & 63;
      s_w[kk][nn] = W[(size_t)(kt * 64 + kk) * N + nt * 64 + nn];
    }
    __syncthreads();
#pragma unroll
    for (int i = 0; i < 16; ++i) {
      int idx = i * 256 + tid;
      int nn = idx >> 6, kk = idx & 63;
      const int n = nt * 64 + nn;
      const float v = s_w[kk][nn];
      const unsigned short hi = f2h(v);
      const unsigned short lo = f2h(v - h2f(hi));
      const int ksw = kt * 64 + (kk ^ ((n & 7) << 3));
      dst[(size_t)n * 512 + ksw] = hi;
      dst[(size_t)n * 512 + 256 + ksw] = lo;
    }
  } else {
    int t = (blk - 536) * 256 + tid;   // 614400 units
    int m = t >> 6, j = (t & 63) * 4;
    float4 v = *reinterpret_cast<const float4*>(hidden + (size_t)m * 256 + j);
    ushort4 h;
    h.x = f2h(v.x); h.y = f2h(v.y); h.z = f2h(v.z); h.w = f2h(v.w);
    *reinterpret_cast<ushort4*>(hidh + (size_t)m * 256 + (j ^ ((m & 7) << 3))) = h;
  }
}

// ---------------------------------------------------------------------------
// Value GEMM (unchanged, proven — 4 blocks/CU).
// ---------------------------------------------------------------------------
__global__ __launch_bounds__(256, 4) void gemm_val_mfma(
    const float* __restrict__ A, const unsigned short* __restrict__ WbfS,
    const float* __restrict__ bias, __hip_bfloat16* __restrict__ C) {
  __shared__ __align__(16) unsigned short Alds[64 * 64];
  __shared__ __align__(16) unsigned short Blds[256 * 64];

  const int t = threadIdx.x;
  const int lane = t & 63;
  const int w = t >> 6;
  const int lm = lane & 15, lg = lane >> 4;
  const int row0 = blockIdx.x * 64;

  f32x4 acc[16];
#pragma unroll
  for (int nf = 0; nf < 16; ++nf) acc[nf] = {0.f, 0.f, 0.f, 0.f};

  for (int k0 = 0; k0 < 256; k0 += 64) {
#pragma unroll
    for (int i = 0; i < 8; ++i) {
      const unsigned short* gp = WbfS +
          (size_t)(w * 64 + i * 8 + (lane >> 3)) * 256 + k0 + (lane & 7) * 8;
      unsigned char* lp = reinterpret_cast<unsigned char*>(Blds) + (w * 8 + i) * 1024;
      __builtin_amdgcn_global_load_lds(
          (const __attribute__((address_space(1))) void*)gp,
          (__attribute__((address_space(3))) void*)lp, 16, 0, 0);
    }
#pragma unroll
    for (int i = 0; i < 4; ++i) {
      int u = i * 256 + t;
      int r = u >> 4, c4 = (u & 15) * 4;
      float4 v = *reinterpret_cast<const float4*>(A + (size_t)(row0 + r) * 256 + k0 + c4);
      ushort4 h;
      h.x = f2bf(v.x); h.y = f2bf(v.y); h.z = f2bf(v.z); h.w = f2bf(v.w);
      *reinterpret_cast<ushort4*>(&Alds[r * 64 + (c4 ^ ((r & 7) << 3))]) = h;
    }
    __syncthreads();

#pragma unroll
    for (int ks = 0; ks < 2; ++ks) {
      const int kk = (ks * 32 + lg * 8) ^ ((lm & 7) << 3);
      const bf16x8 af = *reinterpret_cast<const bf16x8*>(&Alds[(w * 16 + lm) * 64 + kk]);
#pragma unroll
      for (int nf = 0; nf < 16; ++nf) {
        const bf16x8 bfr = *reinterpret_cast<const bf16x8*>(&Blds[(nf * 16 + lm) * 64 + kk]);
        acc[nf] = __builtin_amdgcn_mfma_f32_16x16x32_bf16(af, bfr, acc[nf], 0, 0, 0);
      }
    }
    __syncthreads();
  }

  const int rb = row0 + w * 16 + lg * 4;
#pragma unroll
  for (int nf = 0; nf < 16; ++nf) {
    const int col = nf * 16 + lm;
    const float bv = bias[col];
#pragma unroll
    for (int j = 0; j < 4; ++j)
      C[(size_t)(rb + j) * 256 + col] = __float2bfloat16(acc[nf][j] + bv);
  }
}

// ---------------------------------------------------------------------------
// Generic MFMA GEMM (unchanged): C[M x N] f32 = A[M x KA] @ B[N x KB] + bias.
// ---------------------------------------------------------------------------
template <int KB, int KA, int N, bool F16>
__global__ __launch_bounds__(256) void gemm_tpl(
    const unsigned short* __restrict__ A, const unsigned short* __restrict__ B,
    const float* __restrict__ bias, float* __restrict__ C) {
  __shared__ __align__(16) unsigned short Alds[64 * 64];
  __shared__ __align__(16) unsigned short Blds[N * 64];

  const int t = threadIdx.x;
  const int lane = t & 63;
  const int w = t >> 6;
  const int lm = lane & 15, lg = lane >> 4;
  const int row0 = blockIdx.x * 64;
  constexpr int NF = N / 16;

  f32x4 acc[NF];
#pragma unroll
  for (int nf = 0; nf < NF; ++nf) acc[nf] = {0.f, 0.f, 0.f, 0.f};

  for (int k0 = 0; k0 < KB; k0 += 64) {
    const int ka = k0 & (KA - 1);
#pragma unroll
    for (int i = 0; i < N / 32; ++i) {
      const int c = w * (N / 32) + i;
      const unsigned short* gp = B + (size_t)(c * 8 + (lane >> 3)) * KB + k0 + (lane & 7) * 8;
      unsigned char* lp = reinterpret_cast<unsigned char*>(Blds) + c * 1024;
      __builtin_amdgcn_global_load_lds(
          (const __attribute__((address_space(1))) void*)gp,
          (__attribute__((address_space(3))) void*)lp, 16, 0, 0);
    }
#pragma unroll
    for (int i = 0; i < 2; ++i) {
      const int c = w * 2 + i;
      const unsigned short* gp = A + (size_t)(row0 + c * 8 + (lane >> 3)) * KA + ka + (lane & 7) * 8;
      unsigned char* lp = reinterpret_cast<unsigned char*>(Alds) + c * 1024;
      __builtin_amdgcn_global_load_lds(
          (const __attribute__((address_space(1))) void*)gp,
          (__attribute__((address_space(3))) void*)lp, 16, 0, 0);
    }
    __syncthreads();

#pragma unroll
    for (int ks = 0; ks < 2; ++ks) {
      const int kk = (ks * 32 + lg * 8) ^ ((lm & 7) << 3);
      const bf16x8 af = *reinterpret_cast<const bf16x8*>(&Alds[(w * 16 + lm) * 64 + kk]);
#pragma unroll
      for (int nf = 0; nf < NF; ++nf) {
        const bf16x8 bfr = *reinterpret_cast<const bf16x8*>(&Blds[(nf * 16 + lm) * 64 + kk]);
        if constexpr (F16)
          acc[nf] = __builtin_amdgcn_mfma_f32_16x16x32_f16(
              __builtin_bit_cast(f16x8, af), __builtin_bit_cast(f16x8, bfr), acc[nf], 0, 0, 0);
        else
          acc[nf] = __builtin_amdgcn_mfma_f32_16x16x32_bf16(af, bfr, acc[nf], 0, 0, 0);
      }
    }
    __syncthreads();
  }

  const int rb = row0 + w * 16 + lg * 4;
#pragma unroll
  for (int nf = 0; nf < NF; ++nf) {
    const int col = nf * 16 + lm;
    const float bv = bias[col];
#pragma unroll
    for (int j = 0; j < 4; ++j)
      C[(size_t)(rb + j) * N + col] = acc[nf][j] + bv;
  }
}

// ---------------------------------------------------------------------------
// Sampler v2: 64 threads per query (2 tap-halves x 8 heads x 4 ch-groups).
// Halves the per-thread serial load chain (L3-latency-bound); partials
// combined via LDS. 512 thr, QPB=8, LDS 20KB -> ~4 blocks/CU, 32 waves.
// ---------------------------------------------------------------------------
#define QPB 8

__global__ __launch_bounds__(512) void sample_kernel(
    const __hip_bfloat16* __restrict__ value, const float* __restrict__ offb,
    const float* __restrict__ logits, const float* __restrict__ refpts,
    unsigned short* __restrict__ samp) {
  __shared__ float s_off[QPB][256];   // h-swizzled
  __shared__ float s_lg[QPB][128];
  __shared__ float s_part[QPB][256];

  const int nb = gridDim.x;   // 1200
  const int bswz = (blockIdx.x % 8) * (nb / 8) + blockIdx.x / 8;
  const int bq0 = bswz * QPB;
  const int t = threadIdx.x;

#pragma unroll
  for (int i = 0; i < QPB * 256 / 512; ++i) {
    int idx = i * 512 + t;
    int q = idx >> 8, col = idx & 255;
    s_off[q][col ^ (((col >> 5) & 7) << 2)] = offb[(size_t)bq0 * 256 + idx];
  }
#pragma unroll
  for (int i = 0; i < QPB * 128 / 512; ++i) {
    int idx = i * 512 + t;
    s_lg[idx >> 7][idx & 127] = logits[(size_t)bq0 * 128 + idx];
  }
  __syncthreads();

  if (t < QPB * HH) {   // 64 threads: softmax once per (q,h)
    const int q = t >> 3, h = t & 7;
    float* lg = &s_lg[q][h * 16];
    float m = lg[0];
#pragma unroll
    for (int j = 1; j < 16; ++j) m = fmaxf(m, lg[j]);
    float e[16], s = 0.f;
#pragma unroll
    for (int j = 0; j < 16; ++j) { e[j] = __expf(lg[j] - m); s += e[j]; }
    const float inv = 1.f / s;
#pragma unroll
    for (int j = 0; j < 16; ++j) lg[j] = e[j] * inv;
  }
  __syncthreads();

  const int q = t >> 6;            // 0..7
  const int half = (t >> 5) & 1;   // tap half: l in {0,1} or {2,3}
  const int sub = t & 31;
  const int h = sub >> 2;
  const int c4 = sub & 3;
  const int bq = bq0 + q;
  const int b = bq / QQ;

  const float4 ref = *reinterpret_cast<const float4*>(refpts + (size_t)bq * 4);
  const float rx = ref.x, ry = ref.y, rw = ref.z, rh = ref.w;
  const unsigned short* vb =
      (const unsigned short*)value + (size_t)b * SS * DD + h * DHH + c4 * 8;

  float acc[8];
#pragma unroll
  for (int j = 0; j < 8; ++j) acc[j] = 0.f;

  const int hsw = h << 2;

#pragma unroll
  for (int li = 0; li < 2; ++li) {
    const int dim = half ? (li ? 10 : 20) : (li ? 40 : 80);
    const int st = half ? (li ? 8400 : 8000) : (li ? 6400 : 0);
    const int l = half * 2 + li;
    const float fdim = (float)dim;
#pragma unroll
    for (int p = 0; p < PP; ++p) {
      const int tapi = l * 4 + p;
      const float2 oxy =
          *reinterpret_cast<const float2*>(&s_off[q][(h * 32 + 2 * tapi) ^ hsw]);
      const float locx = rx + oxy.x * rw * 0.125f;
      const float locy = ry + oxy.y * rh * 0.125f;
      const float x = locx * fdim - 0.5f;
      const float y = locy * fdim - 0.5f;
      const float x0f = floorf(x), y0f = floorf(y);
      const float fx = x - x0f, fy = y - y0f;
      const int x0 = (int)x0f, y0 = (int)y0f;
      const float wt = s_lg[q][h * 16 + tapi];
      const float bw[4] = {(1.f - fx) * (1.f - fy), fx * (1.f - fy),
                           (1.f - fx) * fy, fx * fy};
      const int cx[4] = {x0, x0 + 1, x0, x0 + 1};
      const int cy[4] = {y0, y0, y0 + 1, y0 + 1};
#pragma unroll
      for (int c = 0; c < 4; ++c) {
        const int xi = cx[c], yi = cy[c];
        const bool valid = (xi >= 0) & (xi < dim) & (yi >= 0) & (yi < dim);
        const int xc = min(max(xi, 0), dim - 1);
        const int yc = min(max(yi, 0), dim - 1);
        const uint4 v = *reinterpret_cast<const uint4*>(
            vb + (size_t)(st + yc * dim + xc) * DD);
        const float wv = valid ? bw[c] * wt : 0.f;
        const unsigned u[4] = {v.x, v.y, v.z, v.w};
#pragma unroll
        for (int k = 0; k < 4; ++k) {
          const float lo = __builtin_bit_cast(float, u[k] << 16);
          const float hi = __builtin_bit_cast(float, u[k] & 0xFFFF0000u);
          acc[2 * k] += lo * wv;
          acc[2 * k + 1] += hi * wv;
        }
      }
    }
  }

  // combine halves via LDS
  if (half == 1) {
    *reinterpret_cast<float4*>(&s_part[q][h * DHH + c4 * 8]) =
        make_float4(acc[0], acc[1], acc[2], acc[3]);
    *reinterpret_cast<float4*>(&s_part[q][h * DHH + c4 * 8 + 4]) =
        make_float4(acc[4], acc[5], acc[6], acc[7]);
  }
  __syncthreads();
  if (half == 0) {
    const float* pp = &s_part[q][h * DHH + c4 * 8];
    bf16x8 o;
#pragma unroll
    for (int j = 0; j < 8; ++j) o[j] = (short)f2bf(acc[j] + pp[j]);
    const int col = (h * DHH + c4 * 8) ^ ((bq & 7) << 3);
    *reinterpret_cast<bf16x8*>(samp + (size_t)bq * 256 + col) = o;
  }
}

// ---------------------------------------------------------------------------
// Launch
// ---------------------------------------------------------------------------
extern "C" void kernel_launch(void* const* d_in, const int* in_sizes, int n_in,
                              void* d_out, int out_size, void* d_ws, size_t ws_size,
                              hipStream_t stream) {
  const float* hidden = (const float*)d_in[0];
  const float* ehs    = (const float*)d_in[1];
  const float* refpts = (const float*)d_in[2];
  const float* W_val  = (const float*)d_in[3];
  const float* b_val  = (const float*)d_in[4];
  const float* W_off  = (const float*)d_in[5];
  const float* b_off  = (const float*)d_in[6];
  const float* W_attn = (const float*)d_in[7];
  const float* b_attn = (const float*)d_in[8];
  const float* W_out  = (const float*)d_in[9];
  const float* b_out  = (const float*)d_in[10];
  float* out = (float*)d_out;

  // Workspace layout (total ~164.5 MB)
  char* ws = (char*)d_ws;
  __hip_bfloat16* value  = (__hip_bfloat16*)ws;                       // 139,264,000
  unsigned short* wvalS  = (unsigned short*)(ws + 139264000);         // 131,072
  unsigned short* woutS  = (unsigned short*)(ws + 139395072);         // 131,072
  unsigned short* woffE  = (unsigned short*)(ws + 139526144);         // 262,144
  unsigned short* wattE  = (unsigned short*)(ws + 139788288);         // 131,072
  unsigned short* hidh   = (unsigned short*)(ws + 139919360);         // 4,915,200
  float*          offb   = (float*)(ws + 144834560);                  // 9,830,400
  float*          logitsb= (float*)(ws + 154664960);                  // 4,915,200
  unsigned short* samp   = (unsigned short*)(ws + 159580160);         // 4,915,200

  const int M_val = BB * SS;   // 272000
  const int M_q   = BB * QQ;   // 9600

  // 0. all input conversions in one kernel
  prep_kernel<<<2936, 256, 0, stream>>>(W_val, W_out, W_off, W_attn, hidden,
                                        wvalS, woutS, woffE, wattE, hidh);
  // 1. value projection (bf16 MFMA)
  gemm_val_mfma<<<M_val / 64, 256, 0, stream>>>(ehs, wvalS, b_val, value);
  // 2. off / attn projections (f16 MFMA, W-split K=512)
  gemm_tpl<512, 256, 256, true><<<M_q / 64, 256, 0, stream>>>(hidh, woffE, b_off, offb);
  gemm_tpl<512, 256, 128, true><<<M_q / 64, 256, 0, stream>>>(hidh, wattE, b_attn, logitsb);
  // 3. softmax + bilinear sampling -> samp (bf16, swizzled)
  sample_kernel<<<M_q / QPB, 512, 0, stream>>>(value, offb, logitsb, refpts, samp);
  // 4. out projection (bf16 MFMA)
  gemm_tpl<256, 256, 256, false><<<M_q / 64, 256, 0, stream>>>(samp, woutS, b_out, out);
}

// Round 20
// 188.920 us; speedup vs baseline: 2.3045x; 1.0300x over previous
//
#include <hip/hip_runtime.h>
#include <hip/hip_bf16.h>

// Problem constants
#define BB 32
#define QQ 300
#define DD 256
#define HH 8
#define DHH 32
#define LL 4
#define PP 4
#define SS 8500

typedef __attribute__((ext_vector_type(8))) short bf16x8;
typedef __attribute__((ext_vector_type(8))) _Float16 f16x8;
typedef __attribute__((ext_vector_type(4))) float f32x4;

__device__ inline unsigned short f2bf(float f) {
  unsigned int u = __builtin_bit_cast(unsigned int, f);
  unsigned int r = (u + 0x7FFFu + ((u >> 16) & 1u)) >> 16;
  return (unsigned short)r;
}
__device__ inline unsigned short f2h(float f) {
  return __builtin_bit_cast(unsigned short, (_Float16)f);
}
__device__ inline float h2f(unsigned short u) {
  return (float)__builtin_bit_cast(_Float16, u);
}

// ---------------------------------------------------------------------------
// Merged prep kernel:
//   blocks [0,512):    W_val / W_out -> bf16 [n][256] swizzled
//   blocks [512,536):  W_off / W_attn -> f16 hi/lo split [n][512] swizzled
//   blocks [536,2936): hidden -> f16 [m][256] swizzled
//   block  2936:       concat bias [b_off | b_attn] -> biasOA[384]
// ---------------------------------------------------------------------------
__global__ __launch_bounds__(256) void prep_kernel(
    const float* __restrict__ W_val, const float* __restrict__ W_out,
    const float* __restrict__ W_off, const float* __restrict__ W_attn,
    const float* __restrict__ hidden,
    const float* __restrict__ b_off, const float* __restrict__ b_attn,
    unsigned short* __restrict__ wvalS, unsigned short* __restrict__ woutS,
    unsigned short* __restrict__ woffE, unsigned short* __restrict__ wattE,
    unsigned short* __restrict__ hidh, float* __restrict__ biasOA) {
  __shared__ float s_w[64][65];
  const int blk = blockIdx.x;
  const int tid = threadIdx.x;

  if (blk < 512) {
    const float* W = blk < 256 ? W_val : W_out;
    unsigned short* dst = blk < 256 ? wvalS : woutS;
    int t = (blk & 255) * 256 + tid;
    int k = t >> 8, n = t & 255;
    dst[n * 256 + (k ^ ((n & 7) << 3))] = f2bf(W[(size_t)k * 256 + n]);
  } else if (blk < 536) {
    const bool isOff = blk < 528;
    const int N = isOff ? 256 : 128;
    const int NT = N / 64;
    const int lb = isOff ? blk - 512 : blk - 528;
    const float* W = isOff ? W_off : W_attn;
    unsigned short* dst = isOff ? woffE : wattE;
    const int kt = lb / NT, nt = lb % NT;
#pragma unroll
    for (int i = 0; i < 16; ++i) {
      int idx = i * 256 + tid;
      int kk = idx >> 6, nn = idx & 63;
      s_w[kk][nn] = W[(size_t)(kt * 64 + kk) * N + nt * 64 + nn];
    }
    __syncthreads();
#pragma unroll
    for (int i = 0; i < 16; ++i) {
      int idx = i * 256 + tid;
      int nn = idx >> 6, kk = idx & 63;
      const int n = nt * 64 + nn;
      const float v = s_w[kk][nn];
      const unsigned short hi = f2h(v);
      const unsigned short lo = f2h(v - h2f(hi));
      const int ksw = kt * 64 + (kk ^ ((n & 7) << 3));
      dst[(size_t)n * 512 + ksw] = hi;
      dst[(size_t)n * 512 + 256 + ksw] = lo;
    }
  } else if (blk < 2936) {
    int t = (blk - 536) * 256 + tid;   // 614400 units
    int m = t >> 6, j = (t & 63) * 4;
    float4 v = *reinterpret_cast<const float4*>(hidden + (size_t)m * 256 + j);
    ushort4 h;
    h.x = f2h(v.x); h.y = f2h(v.y); h.z = f2h(v.z); h.w = f2h(v.w);
    *reinterpret_cast<ushort4*>(hidh + (size_t)m * 256 + (j ^ ((m & 7) << 3))) = h;
  } else {
    biasOA[tid] = b_off[tid];
    if (tid < 128) biasOA[256 + tid] = b_attn[tid];
  }
}

// ---------------------------------------------------------------------------
// Value GEMM (unchanged, proven — 4 blocks/CU).
// ---------------------------------------------------------------------------
__global__ __launch_bounds__(256, 4) void gemm_val_mfma(
    const float* __restrict__ A, const unsigned short* __restrict__ WbfS,
    const float* __restrict__ bias, __hip_bfloat16* __restrict__ C) {
  __shared__ __align__(16) unsigned short Alds[64 * 64];
  __shared__ __align__(16) unsigned short Blds[256 * 64];

  const int t = threadIdx.x;
  const int lane = t & 63;
  const int w = t >> 6;
  const int lm = lane & 15, lg = lane >> 4;
  const int row0 = blockIdx.x * 64;

  f32x4 acc[16];
#pragma unroll
  for (int nf = 0; nf < 16; ++nf) acc[nf] = {0.f, 0.f, 0.f, 0.f};

  for (int k0 = 0; k0 < 256; k0 += 64) {
#pragma unroll
    for (int i = 0; i < 8; ++i) {
      const unsigned short* gp = WbfS +
          (size_t)(w * 64 + i * 8 + (lane >> 3)) * 256 + k0 + (lane & 7) * 8;
      unsigned char* lp = reinterpret_cast<unsigned char*>(Blds) + (w * 8 + i) * 1024;
      __builtin_amdgcn_global_load_lds(
          (const __attribute__((address_space(1))) void*)gp,
          (__attribute__((address_space(3))) void*)lp, 16, 0, 0);
    }
#pragma unroll
    for (int i = 0; i < 4; ++i) {
      int u = i * 256 + t;
      int r = u >> 4, c4 = (u & 15) * 4;
      float4 v = *reinterpret_cast<const float4*>(A + (size_t)(row0 + r) * 256 + k0 + c4);
      ushort4 h;
      h.x = f2bf(v.x); h.y = f2bf(v.y); h.z = f2bf(v.z); h.w = f2bf(v.w);
      *reinterpret_cast<ushort4*>(&Alds[r * 64 + (c4 ^ ((r & 7) << 3))]) = h;
    }
    __syncthreads();

#pragma unroll
    for (int ks = 0; ks < 2; ++ks) {
      const int kk = (ks * 32 + lg * 8) ^ ((lm & 7) << 3);
      const bf16x8 af = *reinterpret_cast<const bf16x8*>(&Alds[(w * 16 + lm) * 64 + kk]);
#pragma unroll
      for (int nf = 0; nf < 16; ++nf) {
        const bf16x8 bfr = *reinterpret_cast<const bf16x8*>(&Blds[(nf * 16 + lm) * 64 + kk]);
        acc[nf] = __builtin_amdgcn_mfma_f32_16x16x32_bf16(af, bfr, acc[nf], 0, 0, 0);
      }
    }
    __syncthreads();
  }

  const int rb = row0 + w * 16 + lg * 4;
#pragma unroll
  for (int nf = 0; nf < 16; ++nf) {
    const int col = nf * 16 + lm;
    const float bv = bias[col];
#pragma unroll
    for (int j = 0; j < 4; ++j)
      C[(size_t)(rb + j) * 256 + col] = __float2bfloat16(acc[nf][j] + bv);
  }
}

// ---------------------------------------------------------------------------
// Generic MFMA GEMM: C f32 = A[M x KA] @ B[N x KB] + bias.
// Split epilogue: cols [0,NSPLIT) -> C (row stride NSPLIT),
//                 cols [NSPLIT,N) -> C2 (row stride N-NSPLIT).
// (plain `if` on unrolled nf — folds to constant per iteration)
// ---------------------------------------------------------------------------
template <int KB, int KA, int N, int NSPLIT, bool F16>
__global__ __launch_bounds__(256) void gemm_tpl(
    const unsigned short* __restrict__ A, const unsigned short* __restrict__ B,
    const float* __restrict__ bias, float* __restrict__ C,
    float* __restrict__ C2) {
  __shared__ __align__(16) unsigned short Alds[64 * 64];
  __shared__ __align__(16) unsigned short Blds[N * 64];

  const int t = threadIdx.x;
  const int lane = t & 63;
  const int w = t >> 6;
  const int lm = lane & 15, lg = lane >> 4;
  const int row0 = blockIdx.x * 64;
  constexpr int NF = N / 16;

  f32x4 acc[NF];
#pragma unroll
  for (int nf = 0; nf < NF; ++nf) acc[nf] = {0.f, 0.f, 0.f, 0.f};

  for (int k0 = 0; k0 < KB; k0 += 64) {
    const int ka = k0 & (KA - 1);
#pragma unroll
    for (int i = 0; i < N / 32; ++i) {
      const int c = w * (N / 32) + i;
      const unsigned short* gp = B + (size_t)(c * 8 + (lane >> 3)) * KB + k0 + (lane & 7) * 8;
      unsigned char* lp = reinterpret_cast<unsigned char*>(Blds) + c * 1024;
      __builtin_amdgcn_global_load_lds(
          (const __attribute__((address_space(1))) void*)gp,
          (__attribute__((address_space(3))) void*)lp, 16, 0, 0);
    }
#pragma unroll
    for (int i = 0; i < 2; ++i) {
      const int c = w * 2 + i;
      const unsigned short* gp = A + (size_t)(row0 + c * 8 + (lane >> 3)) * KA + ka + (lane & 7) * 8;
      unsigned char* lp = reinterpret_cast<unsigned char*>(Alds) + c * 1024;
      __builtin_amdgcn_global_load_lds(
          (const __attribute__((address_space(1))) void*)gp,
          (__attribute__((address_space(3))) void*)lp, 16, 0, 0);
    }
    __syncthreads();

#pragma unroll
    for (int ks = 0; ks < 2; ++ks) {
      const int kk = (ks * 32 + lg * 8) ^ ((lm & 7) << 3);
      const bf16x8 af = *reinterpret_cast<const bf16x8*>(&Alds[(w * 16 + lm) * 64 + kk]);
#pragma unroll
      for (int nf = 0; nf < NF; ++nf) {
        const bf16x8 bfr = *reinterpret_cast<const bf16x8*>(&Blds[(nf * 16 + lm) * 64 + kk]);
        if constexpr (F16)
          acc[nf] = __builtin_amdgcn_mfma_f32_16x16x32_f16(
              __builtin_bit_cast(f16x8, af), __builtin_bit_cast(f16x8, bfr), acc[nf], 0, 0, 0);
        else
          acc[nf] = __builtin_amdgcn_mfma_f32_16x16x32_bf16(af, bfr, acc[nf], 0, 0, 0);
      }
    }
    __syncthreads();
  }

  const int rb = row0 + w * 16 + lg * 4;
#pragma unroll
  for (int nf = 0; nf < NF; ++nf) {
    const int col = nf * 16 + lm;
    const float bv = bias[col];
    if (nf * 16 < NSPLIT) {   // constant-folds per unrolled iteration
#pragma unroll
      for (int j = 0; j < 4; ++j)
        C[(size_t)(rb + j) * NSPLIT + col] = acc[nf][j] + bv;
    } else {
#pragma unroll
      for (int j = 0; j < 4; ++j)
        C2[(size_t)(rb + j) * (N - NSPLIT) + (col - NSPLIT)] = acc[nf][j] + bv;
    }
  }
}

// ---------------------------------------------------------------------------
// Sampler (R17 structure): 64 threads/query, softmax once per (q,h).
// ---------------------------------------------------------------------------
#define QPB 8

__global__ __launch_bounds__(512) void sample_kernel(
    const __hip_bfloat16* __restrict__ value, const float* __restrict__ offb,
    const float* __restrict__ logits, const float* __restrict__ refpts,
    unsigned short* __restrict__ samp) {
  __shared__ float s_off[QPB][256];   // h-swizzled
  __shared__ float s_lg[QPB][128];
  __shared__ float s_part[QPB][256];

  const int nb = gridDim.x;   // 1200
  const int bswz = (blockIdx.x % 8) * (nb / 8) + blockIdx.x / 8;
  const int bq0 = bswz * QPB;
  const int t = threadIdx.x;

#pragma unroll
  for (int i = 0; i < QPB * 256 / 512; ++i) {
    int idx = i * 512 + t;
    int q = idx >> 8, col = idx & 255;
    s_off[q][col ^ (((col >> 5) & 7) << 2)] = offb[(size_t)bq0 * 256 + idx];
  }
#pragma unroll
  for (int i = 0; i < QPB * 128 / 512; ++i) {
    int idx = i * 512 + t;
    s_lg[idx >> 7][idx & 127] = logits[(size_t)bq0 * 128 + idx];
  }
  __syncthreads();

  if (t < QPB * HH) {   // softmax once per (q,h)
    const int q = t >> 3, h = t & 7;
    float* lg = &s_lg[q][h * 16];
    float m = lg[0];
#pragma unroll
    for (int j = 1; j < 16; ++j) m = fmaxf(m, lg[j]);
    float e[16], s = 0.f;
#pragma unroll
    for (int j = 0; j < 16; ++j) { e[j] = __expf(lg[j] - m); s += e[j]; }
    const float inv = 1.f / s;
#pragma unroll
    for (int j = 0; j < 16; ++j) lg[j] = e[j] * inv;
  }
  __syncthreads();

  const int q = t >> 6;
  const int half = (t >> 5) & 1;
  const int sub = t & 31;
  const int h = sub >> 2;
  const int c4 = sub & 3;
  const int bq = bq0 + q;
  const int b = bq / QQ;

  const float4 ref = *reinterpret_cast<const float4*>(refpts + (size_t)bq * 4);
  const float rx = ref.x, ry = ref.y, rw = ref.z, rh = ref.w;
  const unsigned short* vb =
      (const unsigned short*)value + (size_t)b * SS * DD + h * DHH + c4 * 8;

  float acc[8];
#pragma unroll
  for (int j = 0; j < 8; ++j) acc[j] = 0.f;

  const int hsw = h << 2;

#pragma unroll
  for (int li = 0; li < 2; ++li) {
    const int dim = half ? (li ? 10 : 20) : (li ? 40 : 80);
    const int st = half ? (li ? 8400 : 8000) : (li ? 6400 : 0);
    const int l = half * 2 + li;
    const float fdim = (float)dim;
#pragma unroll
    for (int p = 0; p < PP; ++p) {
      const int tapi = l * 4 + p;
      const float2 oxy =
          *reinterpret_cast<const float2*>(&s_off[q][(h * 32 + 2 * tapi) ^ hsw]);
      const float locx = rx + oxy.x * rw * 0.125f;
      const float locy = ry + oxy.y * rh * 0.125f;
      const float x = locx * fdim - 0.5f;
      const float y = locy * fdim - 0.5f;
      const float x0f = floorf(x), y0f = floorf(y);
      const float fx = x - x0f, fy = y - y0f;
      const int x0 = (int)x0f, y0 = (int)y0f;
      const float wt = s_lg[q][h * 16 + tapi];
      const float bw[4] = {(1.f - fx) * (1.f - fy), fx * (1.f - fy),
                           (1.f - fx) * fy, fx * fy};
      const int cx[4] = {x0, x0 + 1, x0, x0 + 1};
      const int cy[4] = {y0, y0, y0 + 1, y0 + 1};
#pragma unroll
      for (int c = 0; c < 4; ++c) {
        const int xi = cx[c], yi = cy[c];
        const bool valid = (xi >= 0) & (xi < dim) & (yi >= 0) & (yi < dim);
        const int xc = min(max(xi, 0), dim - 1);
        const int yc = min(max(yi, 0), dim - 1);
        const uint4 v = *reinterpret_cast<const uint4*>(
            vb + (size_t)(st + yc * dim + xc) * DD);
        const float wv = valid ? bw[c] * wt : 0.f;
        const unsigned u[4] = {v.x, v.y, v.z, v.w};
#pragma unroll
        for (int k = 0; k < 4; ++k) {
          const float lo = __builtin_bit_cast(float, u[k] << 16);
          const float hi = __builtin_bit_cast(float, u[k] & 0xFFFF0000u);
          acc[2 * k] += lo * wv;
          acc[2 * k + 1] += hi * wv;
        }
      }
    }
  }

  if (half == 1) {
    *reinterpret_cast<float4*>(&s_part[q][h * DHH + c4 * 8]) =
        make_float4(acc[0], acc[1], acc[2], acc[3]);
    *reinterpret_cast<float4*>(&s_part[q][h * DHH + c4 * 8 + 4]) =
        make_float4(acc[4], acc[5], acc[6], acc[7]);
  }
  __syncthreads();
  if (half == 0) {
    const float* pp = &s_part[q][h * DHH + c4 * 8];
    bf16x8 o;
#pragma unroll
    for (int j = 0; j < 8; ++j) o[j] = (short)f2bf(acc[j] + pp[j]);
    const int col = (h * DHH + c4 * 8) ^ ((bq & 7) << 3);
    *reinterpret_cast<bf16x8*>(samp + (size_t)bq * 256 + col) = o;
  }
}

// ---------------------------------------------------------------------------
// Launch
// ---------------------------------------------------------------------------
extern "C" void kernel_launch(void* const* d_in, const int* in_sizes, int n_in,
                              void* d_out, int out_size, void* d_ws, size_t ws_size,
                              hipStream_t stream) {
  const float* hidden = (const float*)d_in[0];
  const float* ehs    = (const float*)d_in[1];
  const float* refpts = (const float*)d_in[2];
  const float* W_val  = (const float*)d_in[3];
  const float* b_val  = (const float*)d_in[4];
  const float* W_off  = (const float*)d_in[5];
  const float* b_off  = (const float*)d_in[6];
  const float* W_attn = (const float*)d_in[7];
  const float* b_attn = (const float*)d_in[8];
  const float* W_out  = (const float*)d_in[9];
  const float* b_out  = (const float*)d_in[10];
  float* out = (float*)d_out;

  // Workspace layout (total ~164.5 MB)
  char* ws = (char*)d_ws;
  __hip_bfloat16* value  = (__hip_bfloat16*)ws;                       // 139,264,000
  unsigned short* wvalS  = (unsigned short*)(ws + 139264000);         // 131,072
  unsigned short* woutS  = (unsigned short*)(ws + 139395072);         // 131,072
  unsigned short* woffE  = (unsigned short*)(ws + 139526144);         // 262,144  (adjacent
  unsigned short* wattE  = (unsigned short*)(ws + 139788288);         // 131,072   to woffE)
  unsigned short* hidh   = (unsigned short*)(ws + 139919360);         // 4,915,200
  float*          offb   = (float*)(ws + 144834560);                  // 9,830,400
  float*          logitsb= (float*)(ws + 154664960);                  // 4,915,200
  unsigned short* samp   = (unsigned short*)(ws + 159580160);         // 4,915,200
  float*          biasOA = (float*)(ws + 164495360);                  // 1,536

  const int M_val = BB * SS;   // 272000
  const int M_q   = BB * QQ;   // 9600

  // 0. all input conversions + bias concat in one kernel
  prep_kernel<<<2937, 256, 0, stream>>>(W_val, W_out, W_off, W_attn, hidden,
                                        b_off, b_attn,
                                        wvalS, woutS, woffE, wattE, hidh, biasOA);
  // 1. value projection (bf16 MFMA)
  gemm_val_mfma<<<M_val / 64, 256, 0, stream>>>(ehs, wvalS, b_val, value);
  // 2. merged off+attn projection (f16 MFMA, N=384, split epilogue)
  gemm_tpl<512, 256, 384, 256, true><<<M_q / 64, 256, 0, stream>>>(
      hidh, woffE, biasOA, offb, logitsb);
  // 3. softmax + bilinear sampling -> samp (bf16, swizzled)
  sample_kernel<<<M_q / QPB, 512, 0, stream>>>(value, offb, logitsb, refpts, samp);
  // 4. out projection (bf16 MFMA)
  gemm_tpl<256, 256, 256, 256, false><<<M_q / 64, 256, 0, stream>>>(
      samp, woutS, b_out, out, nullptr);
}